// Round 1
// baseline (606.488 us; speedup 1.0000x reference)
//
#include <hip/hip_runtime.h>
#include <stdint.h>

typedef unsigned int       u32;
typedef unsigned long long u64;
typedef unsigned short     u16;

typedef float f32x4 __attribute__((ext_vector_type(4)));
typedef short s16x8 __attribute__((ext_vector_type(8)));

#define AS1 __attribute__((address_space(1)))
#define AS3 __attribute__((address_space(3)))

constexpr int BATCH = 8, SEQ = 2048, DIM = 512, CODES = 8192;
constexpr int MROWS = BATCH * SEQ;          // 16384
constexpr int CAP   = 128;                  // candidate slots per row
#define MARGIN          1.0f                // append margin (~16 sigma of bf16 dot err)
#define RESCORE_MARGIN  0.6f                // exact-rescore filter (~8 sigma)

// counted vmcnt + raw barrier (no vmcnt(0)/lgkmcnt(0) drain like __syncthreads)
#define VMCNT(N) asm volatile("s_waitcnt vmcnt(" #N ")" ::: "memory")
#define SBAR()                                    \
    do {                                          \
        __builtin_amdgcn_sched_barrier(0);        \
        __builtin_amdgcn_s_barrier();             \
        __builtin_amdgcn_sched_barrier(0);        \
    } while (0)

// ---- ordered-uint encode for float min ----
__device__ __forceinline__ u32 encf(float f) {
    u32 u = __float_as_uint(f);
    return (u & 0x80000000u) ? ~u : (u | 0x80000000u);
}
__device__ __forceinline__ float decf(u32 e) {
    return (e & 0x80000000u) ? __uint_as_float(e & 0x7fffffffu) : __uint_as_float(~e);
}
__device__ __forceinline__ u16 f2bf(float f) {           // RTNE, finite inputs
    u32 u = __float_as_uint(f);
    return (u16)((u + 0x7fffu + ((u >> 16) & 1u)) >> 16);
}

// ---------------- pass 0: fused fp32->bf16 cast + numpy-pairwise-exact row sumsq ----------------
__global__ __launch_bounds__(256) void k_prep(const float* __restrict__ x,
                                              const float* __restrict__ cb,
                                              u16* __restrict__ dx,
                                              u16* __restrict__ dcb,
                                              float* __restrict__ x2,
                                              float* __restrict__ c2,
                                              u32* __restrict__ cnt) {
#pragma clang fp contract(off)
    __shared__ float lp[64 * 133];
    const int t  = threadIdx.x;
    const int bx = blockIdx.x;
    const int gid = bx * 256 + t;
    if (gid < MROWS) cnt[gid] = 0u;

    const float* src; u16* dst; float* dsq; int row0;
    if (bx < 256) { src = x;  dst = dx;  dsq = x2; row0 = bx * 64; }
    else          { src = cb; dst = dcb; dsq = c2; row0 = (bx - 256) * 64; }

    float blk[4];
    for (int p = 0; p < 4; p++) {
#pragma unroll
        for (int k = 0; k < 8; k++) {
            int idx = t + 256 * k;
            int row = idx >> 5, c4 = idx & 31;
            const float* gp = src + (size_t)(row0 + row) * DIM + p * 128 + c4 * 4;
            float4 v = *(const float4*)gp;
            u64 pk = (u64)f2bf(v.x) | ((u64)f2bf(v.y) << 16) |
                     ((u64)f2bf(v.z) << 32) | ((u64)f2bf(v.w) << 48);
            *(u64*)(dst + (size_t)(row0 + row) * DIM + p * 128 + c4 * 4) = pk;
            int la = row * 133 + c4 * 4;
            lp[la] = v.x; lp[la + 1] = v.y; lp[la + 2] = v.z; lp[la + 3] = v.w;
        }
        __syncthreads();
        if (t < 64) {
            const float* q = lp + t * 133;
            float a0 = q[0]*q[0], a1 = q[1]*q[1], a2 = q[2]*q[2], a3 = q[3]*q[3];
            float a4 = q[4]*q[4], a5 = q[5]*q[5], a6 = q[6]*q[6], a7 = q[7]*q[7];
            for (int i = 1; i < 16; i++) {
                const float* r = q + i * 8;
                a0 = a0 + r[0]*r[0]; a1 = a1 + r[1]*r[1];
                a2 = a2 + r[2]*r[2]; a3 = a3 + r[3]*r[3];
                a4 = a4 + r[4]*r[4]; a5 = a5 + r[5]*r[5];
                a6 = a6 + r[6]*r[6]; a7 = a7 + r[7]*r[7];
            }
            blk[p] = ((a0 + a1) + (a2 + a3)) + ((a4 + a5) + (a6 + a7));
        }
        __syncthreads();
    }
    if (t < 64) dsq[row0 + t] = (blk[0] + blk[1]) + (blk[2] + blk[3]);
}

// ---------------- pass 1: 256x256-tile bf16 MFMA GEMM, 8-phase counted-vmcnt schedule ----------------
// grid = 2048 = 64 row-tiles x 32 col-tiles; block = 512 threads (8 waves, 2Mx4N).
// K = 512 -> 8 K-tiles of BK=64, LDS double-buffered by K-tile parity (2 x (A 32K | B 32K)).
//
// Each K-tile = 4 phases of 16 MFMA (quadrants ih{0,1} x jh{0,1}); per phase:
//   [ds_read next-needed frags | stage one 16-KiB unit] -> s_barrier -> setprio(1) 16xMFMA setprio(0) -> s_barrier
// Staging units per K-tile kt (2 global_load_lds_dwordx4/thread each):
//   alpha = A rows {0-63,128-191}   issued at (kt-2).P1
//   B0    = B rows {0-31,64-95,128-159,192-223} (jh0 slices) at (kt-2).P2
//   beta  = A rows {64-127,192-255} at (kt-2).P3
//   B1    = B jh1 slices            at (kt-1).P0
// Single counted VMCNT(4) per K-tile at P2-end (allows {alpha,B0}(kt+2) = 4 loads in
// flight; forces everything older done) => tile kt+1 fully resident before its first
// read, which is issued one phase early (at kt.P3) so no ds_read latency is exposed.
// All LDS regions verified WAR/RAW-safe against the retirement order of reads:
//   R0(kt)@ (kt-1).P3 reads {alpha,B0};  P0 reads B1;  P1 reads beta.
// vmcnt(0) only once, at kt==6 (tail drain); epilogue __syncthreads covers the rest.
__global__ __launch_bounds__(512, 2) void k_vq(const u16* __restrict__ A,   // [16384,512] bf16
                                               const u16* __restrict__ B,   // [8192,512] bf16
                                               const float* __restrict__ c2,
                                               u32* __restrict__ cnt,
                                               uint2* __restrict__ cand) {
    __shared__ u16 lds[2 * 32768];          // [buf][A 16K u16 | B 16K u16] = 128 KiB
    __shared__ u32 mrow[256];

    const int t    = threadIdx.x;
    const int wave = t >> 6, lane = t & 63;
    const int lr   = lane & 15, quad = lane >> 4;
    const int bx   = blockIdx.x;
    const int swz  = (bx & 7) * 256 + (bx >> 3);   // XCD-bijective swizzle (2048 % 8 == 0):
    const int row0 = (swz & 63) * 256;             // each XCD holds 4 B col-panels (1 MiB) L2-hot
    const int col0 = (swz >> 6) * 256;
    const int wRow = (wave >> 2) * 128;     // 2 row-bands
    const int wCol = (wave & 3) * 64;       // 4 col-bands
    const int s0   = (quad ^ (lr & 7)) * 8; // swizzled u16 chunk offset, kk=0

    if (t < 256) mrow[t] = 0xFFFFFFFFu;

    f32x4 acc[8][4];
#pragma unroll
    for (int i = 0; i < 8; i++)
#pragma unroll
        for (int j = 0; j < 4; j++) { f32x4 z = {0.f, 0.f, 0.f, 0.f}; acc[i][j] = z; }

    const int rl = t >> 3, cp = t & 7;      // staging thread -> (row, 16B-chunk)

    // one 16-KiB A unit: rows [rbase,rbase+64) U [rbase+128,rbase+192)
    auto stageA = [&](int kt, int rbase) {
        const int bo = (kt & 1) * 65536;
#pragma unroll
        for (int h = 0; h < 2; h++) {
            const int rr  = rbase + rl + h * 128;
            const int off = bo + rr * 128 + cp * 16;
            const int sc  = (cp ^ (rr & 7)) * 8;              // XOR-swizzled source col
            const u16* ga = A + (size_t)(row0 + rr) * DIM + kt * 64 + sc;
            __builtin_amdgcn_global_load_lds((const AS1 u32*)ga,
                                             (AS3 u32*)((char*)lds + off), 16, 0, 0);
        }
    };
    // one 16-KiB B unit: jh slices; rbase=0 -> rows {0-31,64-95,...}, rbase=32 -> {32-63,96-127,...}
    auto stageB = [&](int kt, int rbase) {
        const int bo = (kt & 1) * 65536 + 32768;
#pragma unroll
        for (int h = 0; h < 2; h++) {
            const int rr  = rbase + rl + (rl & 32) + h * 128;
            const int off = bo + rr * 128 + cp * 16;
            const int sc  = (cp ^ (rr & 7)) * 8;
            const u16* gb = B + (size_t)(col0 + rr) * DIM + kt * 64 + sc;
            __builtin_amdgcn_global_load_lds((const AS1 u32*)gb,
                                             (AS3 u32*)((char*)lds + off), 16, 0, 0);
        }
    };

    s16x8 aI0[4][2], aI1[4][2], bJ0[2][2], bJ1[2][2];

    auto readA = [&](s16x8 (&dst)[4][2], const u16* base, int ib) {
#pragma unroll
        for (int kk = 0; kk < 2; kk++) {
            const int soff = s0 ^ (kk * 32);
#pragma unroll
            for (int i = 0; i < 4; i++)
                dst[i][kk] = *(const s16x8*)&base[(wRow + (ib + i) * 16 + lr) * 64 + soff];
        }
    };
    auto readB = [&](s16x8 (&dst)[2][2], const u16* base, int jb) {
#pragma unroll
        for (int kk = 0; kk < 2; kk++) {
            const int soff = s0 ^ (kk * 32);
#pragma unroll
            for (int j = 0; j < 2; j++)
                dst[j][kk] = *(const s16x8*)&base[(wCol + (jb + j) * 16 + lr) * 64 + soff];
        }
    };

#define MFMA_Q(AF, BF, IO, JO)                                                  \
    __builtin_amdgcn_s_setprio(1);                                              \
    _Pragma("unroll")                                                           \
    for (int kk = 0; kk < 2; kk++)                                              \
        _Pragma("unroll")                                                       \
        for (int i = 0; i < 4; i++)                                             \
            _Pragma("unroll")                                                   \
            for (int j = 0; j < 2; j++)                                         \
                acc[(IO) + i][(JO) + j] = __builtin_amdgcn_mfma_f32_16x16x32_bf16( \
                    AF[i][kk], BF[j][kk], acc[(IO) + i][(JO) + j], 0, 0, 0);    \
    __builtin_amdgcn_s_setprio(0);

    // ---- prologue: 7 units (issue order matters for the vmcnt accounting) ----
    stageA(0, 0);  stageB(0, 0);  stageA(0, 64);  stageB(0, 32);   // units(0)
    stageA(1, 0);  stageB(1, 0);  stageA(1, 64);                   // alpha,B0,beta (1)
    VMCNT(4);                           // units(0) resident; {B0,beta}(1) may be in flight
    __builtin_amdgcn_s_barrier();
    readA(aI0, lds, 0);                 // R0(0): ih0 frags of tile 0
    readB(bJ0, lds + 16384, 0);         //        jh0 frags of tile 0

    for (int kt = 0; kt < 8; kt++) {
        const u16* bufA  = lds + (kt & 1) * 32768;
        const u16* bufB  = bufA + 16384;
        const u16* nbufA = lds + ((kt + 1) & 1) * 32768;
        const u16* nbufB = nbufA + 16384;

        // ---- P0: ih0 x jh0 ----
        readB(bJ1, bufB, 2);                    // jh1 of this tile (B1 region, resident)
        if (kt + 1 < 8) stageB(kt + 1, 32);     // B1(kt+1)
        SBAR();
        MFMA_Q(aI0, bJ0, 0, 0)
        SBAR();

        // ---- P1: ih0 x jh1 ----
        readA(aI1, bufA, 4);                    // ih1 of this tile (beta region, resident)
        if (kt + 2 < 8) stageA(kt + 2, 0);      // alpha(kt+2) — A ih0 region retired @R0
        SBAR();
        MFMA_Q(aI0, bJ1, 0, 2)
        SBAR();

        // ---- P2: ih1 x jh0 ----
        if (kt + 2 < 8) stageB(kt + 2, 0);      // B0(kt+2) — B jh0 region retired @R0
        SBAR();
        MFMA_Q(aI1, bJ0, 4, 0)
        if (kt < 6)       { VMCNT(4); }         // forces units(kt+1) landed; 2 units in flight
        else if (kt == 6) { VMCNT(0); }         // tail drain for tile 7
        SBAR();

        // ---- P3: ih1 x jh1  (+ read next tile's R0 under the MFMA) ----
        if (kt + 1 < 8) { readA(aI0, nbufA, 0); readB(bJ0, nbufB, 0); }  // R0(kt+1)
        if (kt + 2 < 8) stageA(kt + 2, 64);     // beta(kt+2) — A ih1 region retired @P1
        SBAR();
        MFMA_Q(aI1, bJ1, 4, 2)
        SBAR();
    }

    // ---- epilogue: row-min over this block's 256 cols -> threshold -> margin-append ----
    float c2v[4];
#pragma unroll
    for (int j = 0; j < 4; j++) c2v[j] = c2[col0 + wCol + j * 16 + lr];

#pragma unroll
    for (int i = 0; i < 8; i++) {
#pragma unroll
        for (int r = 0; r < 4; r++) {
            float v0 = c2v[0] - 2.0f * acc[i][0][r];
            float v1 = c2v[1] - 2.0f * acc[i][1][r];
            float v2 = c2v[2] - 2.0f * acc[i][2][r];
            float v3 = c2v[3] - 2.0f * acc[i][3][r];
            float mn = fminf(fminf(v0, v1), fminf(v2, v3));
#pragma unroll
            for (int mask = 1; mask < 16; mask <<= 1)
                mn = fminf(mn, __shfl_xor(mn, mask));
            if (lr == 0) atomicMin(&mrow[wRow + i * 16 + quad * 4 + r], encf(mn));
        }
    }
    __syncthreads();
#pragma unroll
    for (int i = 0; i < 8; i++) {
#pragma unroll
        for (int r = 0; r < 4; r++) {
            const int lrow = wRow + i * 16 + quad * 4 + r;
            const float th = decf(mrow[lrow]) + MARGIN;
            const int grow = row0 + lrow;
#pragma unroll
            for (int j = 0; j < 4; j++) {
                float s = c2v[j] - 2.0f * acc[i][j][r];
                if (s < th) {
                    u32 idx = atomicAdd(&cnt[grow], 1u);
                    if (idx < CAP)
                        cand[(size_t)grow * CAP + idx] =
                            make_uint2(__float_as_uint(s), (u32)(col0 + wCol + j * 16 + lr));
                }
            }
        }
    }
}

// ---------------- pass 2: exact rescore (fp64 dot, np-fp32 pipeline) + gather + PE ----------------
__global__ __launch_bounds__(256) void k_fin(const float* __restrict__ x,
                                             const float* __restrict__ cb,
                                             const float* __restrict__ c2,
                                             const float* __restrict__ x2,
                                             const u32* __restrict__ cnt,
                                             const uint2* __restrict__ cand,
                                             float* __restrict__ out) {
    const int row  = (blockIdx.x * 256 + threadIdx.x) >> 6;   // one wave per row
    const int lane = threadIdx.x & 63;
    int n = (int)cnt[row];
    if (n > CAP) n = CAP;
    if (n < 0) n = 0;
    const uint2* cd = cand + (size_t)row * CAP;

    float m = 3.4028235e38f;
    for (int i = lane; i < n; i += 64) m = fminf(m, __uint_as_float(cd[i].x));
#pragma unroll
    for (int mask = 32; mask; mask >>= 1) m = fminf(m, __shfl_xor(m, mask));
    const float thr = m + RESCORE_MARGIN;

    const float* xr = x + (size_t)row * DIM + lane * 8;
    float4 xv0 = *(const float4*)xr;
    float4 xv1 = *(const float4*)(xr + 4);
    const float x2v = x2[row];

    u64 best = ~0ull;
    for (int i = 0; i < n; i++) {
        uint2 e = cd[i];
        float sa = __uint_as_float(e.x);
        u32 ci = (e.y < (u32)CODES) ? e.y : 0u;                // harden gather index
        if (sa <= thr) {                                       // wave-uniform branch
            const float* cr = cb + (size_t)ci * DIM + lane * 8;
            float4 c0 = *(const float4*)cr;
            float4 c1 = *(const float4*)(cr + 4);
            double d = (double)xv0.x * c0.x + (double)xv0.y * c0.y +
                       (double)xv0.z * c0.z + (double)xv0.w * c0.w +
                       (double)xv1.x * c1.x + (double)xv1.y * c1.y +
                       (double)xv1.z * c1.z + (double)xv1.w * c1.w;
#pragma unroll
            for (int mask = 32; mask; mask >>= 1) d += __shfl_xor(d, mask);
            float dot = (float)d;
            float s32 = (x2v - 2.0f * dot) + c2[ci];           // np fp32 pipeline
            u64 key = ((u64)encf(s32) << 32) | (u64)ci;        // lowest-index tie-break
            best = best < key ? best : key;
        }
    }
    u32 wcol = (u32)(best & 0xffffffffu);
    if (wcol >= (u32)CODES) wcol = 0;                          // unreachable safety

    const float* cw = cb + (size_t)wcol * DIM + lane * 8;
    float4 q0 = *(const float4*)cw;
    float4 q1 = *(const float4*)(cw + 4);
    const int spos = row & (SEQ - 1);
    float pe[8];
#pragma unroll
    for (int ii = 0; ii < 4; ii++) {
        int ipair = lane * 4 + ii;
        float dt  = expf((float)(2 * ipair) * (-0.017988946039035083f)); // ln(1e4)/512
        float ang = (float)spos * dt;
        float sv, cv;
        sincosf(ang, &sv, &cv);
        pe[2 * ii]     = sv;
        pe[2 * ii + 1] = cv;
    }
    float4* op = (float4*)(out + (size_t)row * DIM + lane * 8);
    op[0] = make_float4(q0.x + pe[0], q0.y + pe[1], q0.z + pe[2], q0.w + pe[3]);
    op[1] = make_float4(q1.x + pe[4], q1.y + pe[5], q1.z + pe[6], q1.w + pe[7]);
}

extern "C" void kernel_launch(void* const* d_in, const int* in_sizes, int n_in,
                              void* d_out, int out_size, void* d_ws, size_t ws_size,
                              hipStream_t stream) {
    const float* x  = (const float*)d_in[0];   // [8,2048,512]
    const float* cb = (const float*)d_in[1];   // [8192,512]
    float* out = (float*)d_out;

    char* ws = (char*)d_ws;
    u16*   Abf  = (u16*)ws;                                   // 16 MiB
    u16*   Bbf  = (u16*)(ws + 16777216);                      //  8 MiB
    float* c2   = (float*)(ws + 16777216 + 8388608);          // 32 KiB
    float* x2   = (float*)(ws + 16777216 + 8388608 + 32768);  // 64 KiB
    u32*   cnt  = (u32*)(ws + 16777216 + 8388608 + 32768 + 65536);            // 64 KiB
    uint2* cand = (uint2*)(ws + 16777216 + 8388608 + 32768 + 65536 + 65536);  // 16 MiB

    k_prep<<<dim3(384), dim3(256), 0, stream>>>(x, cb, Abf, Bbf, x2, c2, cnt);
    k_vq<<<dim3(2048), dim3(512), 0, stream>>>(Abf, Bbf, c2, cnt, cand);
    k_fin<<<dim3(4096), dim3(256), 0, stream>>>(x, cb, c2, x2, cnt, cand, out);
}

// Round 2
// 442.970 us; speedup vs baseline: 1.3691x; 1.3691x over previous
//
#include <hip/hip_runtime.h>
#include <stdint.h>

typedef unsigned int       u32;
typedef unsigned long long u64;
typedef unsigned short     u16;

typedef float f32x4 __attribute__((ext_vector_type(4)));
typedef short s16x8 __attribute__((ext_vector_type(8)));

#define AS1 __attribute__((address_space(1)))
#define AS3 __attribute__((address_space(3)))

constexpr int BATCH = 8, SEQ = 2048, DIM = 512, CODES = 8192;
constexpr int MROWS = BATCH * SEQ;          // 16384
constexpr int CAP   = 128;                  // candidate slots per row
#define MARGIN          1.0f                // append margin (~16 sigma of bf16 dot err)
#define RESCORE_MARGIN  0.6f                // exact-rescore filter (~8 sigma)

// counted vmcnt + raw barrier (no vmcnt(0)/lgkmcnt(0) drain like __syncthreads)
#define VMCNT(N) asm volatile("s_waitcnt vmcnt(" #N ")" ::: "memory")
#define SBAR()                                    \
    do {                                          \
        __builtin_amdgcn_sched_barrier(0);        \
        __builtin_amdgcn_s_barrier();             \
        __builtin_amdgcn_sched_barrier(0);        \
    } while (0)

// ---- ordered-uint encode for float min ----
__device__ __forceinline__ u32 encf(float f) {
    u32 u = __float_as_uint(f);
    return (u & 0x80000000u) ? ~u : (u | 0x80000000u);
}
__device__ __forceinline__ float decf(u32 e) {
    return (e & 0x80000000u) ? __uint_as_float(e & 0x7fffffffu) : __uint_as_float(~e);
}
__device__ __forceinline__ u16 f2bf(float f) {           // RTNE, finite inputs
    u32 u = __float_as_uint(f);
    return (u16)((u + 0x7fffu + ((u >> 16) & 1u)) >> 16);
}

// ---------------- pass 0: fused fp32->bf16 cast + numpy-pairwise-exact row sumsq ----------------
__global__ __launch_bounds__(256) void k_prep(const float* __restrict__ x,
                                              const float* __restrict__ cb,
                                              u16* __restrict__ dx,
                                              u16* __restrict__ dcb,
                                              float* __restrict__ x2,
                                              float* __restrict__ c2,
                                              u32* __restrict__ cnt) {
#pragma clang fp contract(off)
    __shared__ float lp[64 * 133];
    const int t  = threadIdx.x;
    const int bx = blockIdx.x;
    const int gid = bx * 256 + t;
    if (gid < MROWS) cnt[gid] = 0u;

    const float* src; u16* dst; float* dsq; int row0;
    if (bx < 256) { src = x;  dst = dx;  dsq = x2; row0 = bx * 64; }
    else          { src = cb; dst = dcb; dsq = c2; row0 = (bx - 256) * 64; }

    float blk[4];
    for (int p = 0; p < 4; p++) {
#pragma unroll
        for (int k = 0; k < 8; k++) {
            int idx = t + 256 * k;
            int row = idx >> 5, c4 = idx & 31;
            const float* gp = src + (size_t)(row0 + row) * DIM + p * 128 + c4 * 4;
            float4 v = *(const float4*)gp;
            u64 pk = (u64)f2bf(v.x) | ((u64)f2bf(v.y) << 16) |
                     ((u64)f2bf(v.z) << 32) | ((u64)f2bf(v.w) << 48);
            *(u64*)(dst + (size_t)(row0 + row) * DIM + p * 128 + c4 * 4) = pk;
            int la = row * 133 + c4 * 4;
            lp[la] = v.x; lp[la + 1] = v.y; lp[la + 2] = v.z; lp[la + 3] = v.w;
        }
        __syncthreads();
        if (t < 64) {
            const float* q = lp + t * 133;
            float a0 = q[0]*q[0], a1 = q[1]*q[1], a2 = q[2]*q[2], a3 = q[3]*q[3];
            float a4 = q[4]*q[4], a5 = q[5]*q[5], a6 = q[6]*q[6], a7 = q[7]*q[7];
            for (int i = 1; i < 16; i++) {
                const float* r = q + i * 8;
                a0 = a0 + r[0]*r[0]; a1 = a1 + r[1]*r[1];
                a2 = a2 + r[2]*r[2]; a3 = a3 + r[3]*r[3];
                a4 = a4 + r[4]*r[4]; a5 = a5 + r[5]*r[5];
                a6 = a6 + r[6]*r[6]; a7 = a7 + r[7]*r[7];
            }
            blk[p] = ((a0 + a1) + (a2 + a3)) + ((a4 + a5) + (a6 + a7));
        }
        __syncthreads();
    }
    if (t < 64) dsq[row0 + t] = (blk[0] + blk[1]) + (blk[2] + blk[3]);
}

// ---------------- pass 1: 256x256-tile bf16 MFMA GEMM, 8-phase counted-vmcnt schedule ----------------
// grid = 2048; block = 512 threads (8 waves, 2Mx4N). K = 512 -> 8 K-tiles of BK=64,
// LDS double-buffered by tile parity.  Per tile, 4 phases of 16 MFMA:
//   P0 (ih0 x jh0): read a0(8xb128)+b0(4)   | stage B0(kt+1)
//   P1 (ih0 x jh1): read b1(4)              | stage B1(kt+1)
//   P2 (ih1 x jh0): read a1(8, reuses regs) | stage alpha(kt+2)
//   P3 (ih1 x jh1): (no reads)              | stage beta(kt+2); MFMA; VMCNT(4); bar
// Each phase: [reads+stage] SBAR [16 MFMA] SBAR.  Fragments live only within the
// tile (a 32 + b0 16 + b1 16 = 64 VGPR) -- no cross-backedge live ranges (the round-1
// spill cause).  A-units staged 2 tiles ahead (HBM latency), B-units 1 ahead (L2-hot
// under the XCD swizzle).  VMCNT(4) at P3-end forces tile kt+1's 4 units complete
// (they are older than the 2 A-units of kt+2 still in flight); the closing barrier
// then publishes all waves' staging, so kt+1.P0 may read immediately.
// WAR (stage vs last read of the region being overwritten, barrier-separated):
//   B0(kt+1)@P0 vs B0(kt-1)@(kt-1).P0; B1(kt+1)@P1 vs B1(kt-1)@(kt-1).P1;
//   alpha(kt+2)@P2 vs alpha(kt)@P0;    beta(kt+2)@P3 vs beta(kt)@P2.   All safe.
// Tail: VMCNT(0) at kt==6 (tile 7's B-units need full drain); no stage at kt==7.
__global__ __launch_bounds__(512, 2) void k_vq(const u16* __restrict__ A,   // [16384,512] bf16
                                               const u16* __restrict__ B,   // [8192,512] bf16
                                               const float* __restrict__ c2,
                                               u32* __restrict__ cnt,
                                               uint2* __restrict__ cand) {
    __shared__ u16 lds[2 * 32768];          // [buf][A 16K u16 | B 16K u16] = 128 KiB
    __shared__ u32 mrow[256];

    const int t    = threadIdx.x;
    const int wave = t >> 6, lane = t & 63;
    const int lr   = lane & 15, quad = lane >> 4;
    const int bx   = blockIdx.x;
    const int swz  = (bx & 7) * 256 + (bx >> 3);   // XCD-bijective swizzle (2048 % 8 == 0)
    const int row0 = (swz & 63) * 256;
    const int col0 = (swz >> 6) * 256;             // each XCD holds 4 B col-panels (1 MiB) L2-hot
    const int wRow = (wave >> 2) * 128;     // 2 row-bands
    const int wCol = (wave & 3) * 64;       // 4 col-bands
    const int s0   = (quad ^ (lr & 7)) * 8; // swizzled u16 chunk offset, kk=0

    if (t < 256) mrow[t] = 0xFFFFFFFFu;

    f32x4 acc[8][4];
#pragma unroll
    for (int i = 0; i < 8; i++)
#pragma unroll
        for (int j = 0; j < 4; j++) { f32x4 z = {0.f, 0.f, 0.f, 0.f}; acc[i][j] = z; }

    const int rl = t >> 3, cp = t & 7;      // staging thread -> (row, 16B-chunk)

    // one 16-KiB A unit: rbase=0 -> rows {0-63,128-191} (alpha), rbase=64 -> beta
    auto stageA = [&](int kt, int rbase) {
        const int bo = (kt & 1) * 65536;
#pragma unroll
        for (int h = 0; h < 2; h++) {
            const int rr  = rbase + rl + h * 128;
            const int off = bo + rr * 128 + cp * 16;
            const int sc  = (cp ^ (rr & 7)) * 8;              // XOR-swizzled source col
            const u16* ga = A + (size_t)(row0 + rr) * DIM + kt * 64 + sc;
            __builtin_amdgcn_global_load_lds((const AS1 u32*)ga,
                                             (AS3 u32*)((char*)lds + off), 16, 0, 0);
        }
    };
    // one 16-KiB B unit: rbase=0 -> rows {0-31,64-95,128-159,192-223} (B0), rbase=32 -> B1
    auto stageB = [&](int kt, int rbase) {
        const int bo = (kt & 1) * 65536 + 32768;
#pragma unroll
        for (int h = 0; h < 2; h++) {
            const int rr  = rbase + rl + (rl & 32) + h * 128;
            const int off = bo + rr * 128 + cp * 16;
            const int sc  = (cp ^ (rr & 7)) * 8;
            const u16* gb = B + (size_t)(col0 + rr) * DIM + kt * 64 + sc;
            __builtin_amdgcn_global_load_lds((const AS1 u32*)gb,
                                             (AS3 u32*)((char*)lds + off), 16, 0, 0);
        }
    };

    s16x8 aF[4][2], b0F[2][2], b1F[2][2];   // 64 VGPR total, never live across back-edge

    auto readA = [&](s16x8 (&dst)[4][2], const u16* base, int ib) {
#pragma unroll
        for (int kk = 0; kk < 2; kk++) {
            const int soff = s0 ^ (kk * 32);
#pragma unroll
            for (int i = 0; i < 4; i++)
                dst[i][kk] = *(const s16x8*)&base[(wRow + (ib + i) * 16 + lr) * 64 + soff];
        }
    };
    auto readB = [&](s16x8 (&dst)[2][2], const u16* base, int jb) {
#pragma unroll
        for (int kk = 0; kk < 2; kk++) {
            const int soff = s0 ^ (kk * 32);
#pragma unroll
            for (int j = 0; j < 2; j++)
                dst[j][kk] = *(const s16x8*)&base[(wCol + (jb + j) * 16 + lr) * 64 + soff];
        }
    };

#define MFMA_Q(AF, BF, IO, JO)                                                  \
    __builtin_amdgcn_s_setprio(1);                                              \
    _Pragma("unroll")                                                           \
    for (int kk = 0; kk < 2; kk++)                                              \
        _Pragma("unroll")                                                       \
        for (int i = 0; i < 4; i++)                                             \
            _Pragma("unroll")                                                   \
            for (int j = 0; j < 2; j++)                                         \
                acc[(IO) + i][(JO) + j] = __builtin_amdgcn_mfma_f32_16x16x32_bf16( \
                    AF[i][kk], BF[j][kk], acc[(IO) + i][(JO) + j], 0, 0, 0);    \
    __builtin_amdgcn_s_setprio(0);

    // ---- prologue: tile 0 complete (8 loads) + alpha/beta of tile 1 (4 loads) ----
    stageA(0, 0);  stageA(0, 64);  stageB(0, 0);  stageB(0, 32);
    stageA(1, 0);  stageA(1, 64);
    VMCNT(4);                               // tile 0 resident; {alpha,beta}(1) in flight
    SBAR();

    for (int kt = 0; kt < 8; kt++) {
        const u16* bufA = lds + (kt & 1) * 32768;
        const u16* bufB = bufA + 16384;

        // ---- P0: ih0 x jh0 ----
        readA(aF, bufA, 0);                     // alpha(kt): 8 x ds_read_b128
        readB(b0F, bufB, 0);                    // B0(kt):    4 x ds_read_b128
        if (kt + 1 < 8) stageB(kt + 1, 0);
        SBAR();
        MFMA_Q(aF, b0F, 0, 0)
        SBAR();

        // ---- P1: ih0 x jh1 ----
        readB(b1F, bufB, 2);                    // B1(kt)
        if (kt + 1 < 8) stageB(kt + 1, 32);
        SBAR();
        MFMA_Q(aF, b1F, 0, 2)
        SBAR();

        // ---- P2: ih1 x jh0 ----
        readA(aF, bufA, 4);                     // beta(kt), reuses aF registers
        if (kt + 2 < 8) stageA(kt + 2, 0);
        SBAR();
        MFMA_Q(aF, b0F, 4, 0)
        SBAR();

        // ---- P3: ih1 x jh1 ----
        if (kt + 2 < 8) stageA(kt + 2, 64);
        SBAR();
        MFMA_Q(aF, b1F, 4, 2)
        if (kt < 6)       { VMCNT(4); }         // tile kt+1 resident; A-units(kt+2) in flight
        else if (kt == 6) { VMCNT(0); }         // tail drain for tile 7
        SBAR();                                 // publishes staging across waves
    }

    // ---- epilogue: row-min over this block's 256 cols -> threshold -> margin-append ----
    float c2v[4];
#pragma unroll
    for (int j = 0; j < 4; j++) c2v[j] = c2[col0 + wCol + j * 16 + lr];

#pragma unroll
    for (int i = 0; i < 8; i++) {
#pragma unroll
        for (int r = 0; r < 4; r++) {
            float v0 = c2v[0] - 2.0f * acc[i][0][r];
            float v1 = c2v[1] - 2.0f * acc[i][1][r];
            float v2 = c2v[2] - 2.0f * acc[i][2][r];
            float v3 = c2v[3] - 2.0f * acc[i][3][r];
            float mn = fminf(fminf(v0, v1), fminf(v2, v3));
#pragma unroll
            for (int mask = 1; mask < 16; mask <<= 1)
                mn = fminf(mn, __shfl_xor(mn, mask));
            if (lr == 0) atomicMin(&mrow[wRow + i * 16 + quad * 4 + r], encf(mn));
        }
    }
    __syncthreads();
#pragma unroll
    for (int i = 0; i < 8; i++) {
#pragma unroll
        for (int r = 0; r < 4; r++) {
            const int lrow = wRow + i * 16 + quad * 4 + r;
            const float th = decf(mrow[lrow]) + MARGIN;
            const int grow = row0 + lrow;
#pragma unroll
            for (int j = 0; j < 4; j++) {
                float s = c2v[j] - 2.0f * acc[i][j][r];
                if (s < th) {
                    u32 idx = atomicAdd(&cnt[grow], 1u);
                    if (idx < CAP)
                        cand[(size_t)grow * CAP + idx] =
                            make_uint2(__float_as_uint(s), (u32)(col0 + wCol + j * 16 + lr));
                }
            }
        }
    }
}

// ---------------- pass 2: exact rescore (fp64 dot, np-fp32 pipeline) + gather + PE ----------------
__global__ __launch_bounds__(256) void k_fin(const float* __restrict__ x,
                                             const float* __restrict__ cb,
                                             const float* __restrict__ c2,
                                             const float* __restrict__ x2,
                                             const u32* __restrict__ cnt,
                                             const uint2* __restrict__ cand,
                                             float* __restrict__ out) {
    const int row  = (blockIdx.x * 256 + threadIdx.x) >> 6;   // one wave per row
    const int lane = threadIdx.x & 63;
    int n = (int)cnt[row];
    if (n > CAP) n = CAP;
    if (n < 0) n = 0;
    const uint2* cd = cand + (size_t)row * CAP;

    float m = 3.4028235e38f;
    for (int i = lane; i < n; i += 64) m = fminf(m, __uint_as_float(cd[i].x));
#pragma unroll
    for (int mask = 32; mask; mask >>= 1) m = fminf(m, __shfl_xor(m, mask));
    const float thr = m + RESCORE_MARGIN;

    const float* xr = x + (size_t)row * DIM + lane * 8;
    float4 xv0 = *(const float4*)xr;
    float4 xv1 = *(const float4*)(xr + 4);
    const float x2v = x2[row];

    u64 best = ~0ull;
    for (int i = 0; i < n; i++) {
        uint2 e = cd[i];
        float sa = __uint_as_float(e.x);
        u32 ci = (e.y < (u32)CODES) ? e.y : 0u;                // harden gather index
        if (sa <= thr) {                                       // wave-uniform branch
            const float* cr = cb + (size_t)ci * DIM + lane * 8;
            float4 c0 = *(const float4*)cr;
            float4 c1 = *(const float4*)(cr + 4);
            double d = (double)xv0.x * c0.x + (double)xv0.y * c0.y +
                       (double)xv0.z * c0.z + (double)xv0.w * c0.w +
                       (double)xv1.x * c1.x + (double)xv1.y * c1.y +
                       (double)xv1.z * c1.z + (double)xv1.w * c1.w;
#pragma unroll
            for (int mask = 32; mask; mask >>= 1) d += __shfl_xor(d, mask);
            float dot = (float)d;
            float s32 = (x2v - 2.0f * dot) + c2[ci];           // np fp32 pipeline
            u64 key = ((u64)encf(s32) << 32) | (u64)ci;        // lowest-index tie-break
            best = best < key ? best : key;
        }
    }
    u32 wcol = (u32)(best & 0xffffffffu);
    if (wcol >= (u32)CODES) wcol = 0;                          // unreachable safety

    const float* cw = cb + (size_t)wcol * DIM + lane * 8;
    float4 q0 = *(const float4*)cw;
    float4 q1 = *(const float4*)(cw + 4);
    const int spos = row & (SEQ - 1);
    float pe[8];
#pragma unroll
    for (int ii = 0; ii < 4; ii++) {
        int ipair = lane * 4 + ii;
        float dt  = expf((float)(2 * ipair) * (-0.017988946039035083f)); // ln(1e4)/512
        float ang = (float)spos * dt;
        float sv, cv;
        sincosf(ang, &sv, &cv);
        pe[2 * ii]     = sv;
        pe[2 * ii + 1] = cv;
    }
    float4* op = (float4*)(out + (size_t)row * DIM + lane * 8);
    op[0] = make_float4(q0.x + pe[0], q0.y + pe[1], q0.z + pe[2], q0.w + pe[3]);
    op[1] = make_float4(q1.x + pe[4], q1.y + pe[5], q1.z + pe[6], q1.w + pe[7]);
}

extern "C" void kernel_launch(void* const* d_in, const int* in_sizes, int n_in,
                              void* d_out, int out_size, void* d_ws, size_t ws_size,
                              hipStream_t stream) {
    const float* x  = (const float*)d_in[0];   // [8,2048,512]
    const float* cb = (const float*)d_in[1];   // [8192,512]
    float* out = (float*)d_out;

    char* ws = (char*)d_ws;
    u16*   Abf  = (u16*)ws;                                   // 16 MiB
    u16*   Bbf  = (u16*)(ws + 16777216);                      //  8 MiB
    float* c2   = (float*)(ws + 16777216 + 8388608);          // 32 KiB
    float* x2   = (float*)(ws + 16777216 + 8388608 + 32768);  // 64 KiB
    u32*   cnt  = (u32*)(ws + 16777216 + 8388608 + 32768 + 65536);            // 64 KiB
    uint2* cand = (uint2*)(ws + 16777216 + 8388608 + 32768 + 65536 + 65536);  // 16 MiB

    k_prep<<<dim3(384), dim3(256), 0, stream>>>(x, cb, Abf, Bbf, x2, c2, cnt);
    k_vq<<<dim3(2048), dim3(512), 0, stream>>>(Abf, Bbf, c2, cnt, cand);
    k_fin<<<dim3(4096), dim3(256), 0, stream>>>(x, cb, c2, x2, cnt, cand, out);
}

// Round 3
// 438.960 us; speedup vs baseline: 1.3816x; 1.0091x over previous
//
#include <hip/hip_runtime.h>
#include <stdint.h>

typedef unsigned int       u32;
typedef unsigned long long u64;
typedef unsigned short     u16;

typedef float f32x4 __attribute__((ext_vector_type(4)));
typedef short s16x8 __attribute__((ext_vector_type(8)));

#define AS1 __attribute__((address_space(1)))
#define AS3 __attribute__((address_space(3)))

constexpr int BATCH = 8, SEQ = 2048, DIM = 512, CODES = 8192;
constexpr int MROWS = BATCH * SEQ;          // 16384
constexpr int CAP   = 128;                  // candidate slots per row
#define MARGIN          1.0f                // append margin (~16 sigma of bf16 dot err)
#define RESCORE_MARGIN  0.6f                // exact-rescore filter (~8 sigma)

// counted vmcnt (memory clobber = the only compiler-level fence in the loop)
#define VMCNT(N) asm volatile("s_waitcnt vmcnt(" #N ")" ::: "memory")
// plain barrier — NO sched_barrier walls (m141: order-pinning regresses 874->510 TF),
// NO implicit vmcnt(0)/lgkmcnt(0) drain (the whole point vs __syncthreads)
#define BAR() __builtin_amdgcn_s_barrier()

// ---- ordered-uint encode for float min ----
__device__ __forceinline__ u32 encf(float f) {
    u32 u = __float_as_uint(f);
    return (u & 0x80000000u) ? ~u : (u | 0x80000000u);
}
__device__ __forceinline__ float decf(u32 e) {
    return (e & 0x80000000u) ? __uint_as_float(e & 0x7fffffffu) : __uint_as_float(~e);
}
__device__ __forceinline__ u16 f2bf(float f) {           // RTNE, finite inputs
    u32 u = __float_as_uint(f);
    return (u16)((u + 0x7fffu + ((u >> 16) & 1u)) >> 16);
}

// ---------------- pass 0: fused fp32->bf16 cast + numpy-pairwise-exact row sumsq ----------------
__global__ __launch_bounds__(256) void k_prep(const float* __restrict__ x,
                                              const float* __restrict__ cb,
                                              u16* __restrict__ dx,
                                              u16* __restrict__ dcb,
                                              float* __restrict__ x2,
                                              float* __restrict__ c2,
                                              u32* __restrict__ cnt) {
#pragma clang fp contract(off)
    __shared__ float lp[64 * 133];
    const int t  = threadIdx.x;
    const int bx = blockIdx.x;
    const int gid = bx * 256 + t;
    if (gid < MROWS) cnt[gid] = 0u;

    const float* src; u16* dst; float* dsq; int row0;
    if (bx < 256) { src = x;  dst = dx;  dsq = x2; row0 = bx * 64; }
    else          { src = cb; dst = dcb; dsq = c2; row0 = (bx - 256) * 64; }

    float blk[4];
    for (int p = 0; p < 4; p++) {
#pragma unroll
        for (int k = 0; k < 8; k++) {
            int idx = t + 256 * k;
            int row = idx >> 5, c4 = idx & 31;
            const float* gp = src + (size_t)(row0 + row) * DIM + p * 128 + c4 * 4;
            float4 v = *(const float4*)gp;
            u64 pk = (u64)f2bf(v.x) | ((u64)f2bf(v.y) << 16) |
                     ((u64)f2bf(v.z) << 32) | ((u64)f2bf(v.w) << 48);
            *(u64*)(dst + (size_t)(row0 + row) * DIM + p * 128 + c4 * 4) = pk;
            int la = row * 133 + c4 * 4;
            lp[la] = v.x; lp[la + 1] = v.y; lp[la + 2] = v.z; lp[la + 3] = v.w;
        }
        __syncthreads();
        if (t < 64) {
            const float* q = lp + t * 133;
            float a0 = q[0]*q[0], a1 = q[1]*q[1], a2 = q[2]*q[2], a3 = q[3]*q[3];
            float a4 = q[4]*q[4], a5 = q[5]*q[5], a6 = q[6]*q[6], a7 = q[7]*q[7];
            for (int i = 1; i < 16; i++) {
                const float* r = q + i * 8;
                a0 = a0 + r[0]*r[0]; a1 = a1 + r[1]*r[1];
                a2 = a2 + r[2]*r[2]; a3 = a3 + r[3]*r[3];
                a4 = a4 + r[4]*r[4]; a5 = a5 + r[5]*r[5];
                a6 = a6 + r[6]*r[6]; a7 = a7 + r[7]*r[7];
            }
            blk[p] = ((a0 + a1) + (a2 + a3)) + ((a4 + a5) + (a6 + a7));
        }
        __syncthreads();
    }
    if (t < 64) dsq[row0 + t] = (blk[0] + blk[1]) + (blk[2] + blk[3]);
}

// ---------------- pass 1: 256x256-tile bf16 MFMA GEMM, 8-phase counted-vmcnt schedule ----------------
// grid = 2048 natural order (bx&63 = row-tile fast): concurrent blocks on one XCD form an
// 8-row x 4-col cluster -> A+B working set ~3 MiB, L2-resident (round-0 FETCH=65MB evidence;
// the round-2 col-major XCD swizzle streamed 8 MiB of A per XCD and quadrupled FETCH).
// Per tile, 4 phases of 16 MFMA:
//   P0 (ih0 x jh0): read a(ih0,8xb128)+b0(4) | stage B0(kt+1)
//   P1 (ih0 x jh1): read b1(4)               | stage B1(kt+1)
//   P2 (ih1 x jh0): read a(ih1,8; reuse regs)| stage alpha(kt+2)
//   P3 (ih1 x jh1): (no reads)               | stage beta(kt+2); MFMA; VMCNT(4); BAR
// Phase = [reads+stage] BAR [16 MFMA] BAR, plain s_barrier (loads stay in flight across
// barriers; the compiler's own lgkmcnt covers ds_read->MFMA). Single VMCNT(4) per tile at
// P3-end forces tile kt+1's 4 units complete (A(kt+2)'s 4 loads, younger, stay in flight).
// Hoist-safety without sched_barrier: every ds_read's source region is resident at the
// nearest upstream VMCNT fence (alpha/beta staged 2 tiles ahead, B 1 tile ahead), so any
// legal compiler motion still reads valid data. WAR: reads complete (in regs) before the
// phase-closing barrier; the overwriting stage is >=1 barrier later in every case.
// Tail: VMCNT(0) at kt==6; epilogue __syncthreads covers the rest.
__global__ __launch_bounds__(512, 2) void k_vq(const u16* __restrict__ A,   // [16384,512] bf16
                                               const u16* __restrict__ B,   // [8192,512] bf16
                                               const float* __restrict__ c2,
                                               u32* __restrict__ cnt,
                                               uint2* __restrict__ cand) {
    __shared__ u16 lds[2 * 32768];          // [buf][A 16K u16 | B 16K u16] = 128 KiB
    __shared__ u32 mrow[256];

    const int t    = threadIdx.x;
    const int wave = t >> 6, lane = t & 63;
    const int lr   = lane & 15, quad = lane >> 4;
    const int bx   = blockIdx.x;
    const int row0 = (bx & 63) * 256;       // natural order (see header comment)
    const int col0 = (bx >> 6) * 256;
    const int wRow = (wave >> 2) * 128;     // 2 row-bands
    const int wCol = (wave & 3) * 64;       // 4 col-bands
    const int s0   = (quad ^ (lr & 7)) * 8; // swizzled u16 chunk offset, kk=0

    if (t < 256) mrow[t] = 0xFFFFFFFFu;

    f32x4 acc[8][4];
#pragma unroll
    for (int i = 0; i < 8; i++)
#pragma unroll
        for (int j = 0; j < 4; j++) { f32x4 z = {0.f, 0.f, 0.f, 0.f}; acc[i][j] = z; }

    // ---- staging addresses, hoisted out of the K-loop ----
    // thread t -> (row-in-unit rl, 16B chunk cp); XOR source-col swizzle: rr&7 == rl&7
    // for every unit (rbase,h offsets are multiples of 8), so scX is unit-invariant.
    const int rl = t >> 3, cp = t & 7;
    const int scX = (cp ^ (rl & 7)) * 8;                 // u16 source column offset
    size_t gOffA[2][2], gOffB[2][2];                     // global element offsets (kt=0)
    int    lOffA[2][2], lOffB[2][2];                     // LDS byte offsets (buf 0)
#pragma unroll
    for (int h = 0; h < 2; h++) {
#pragma unroll
        for (int u = 0; u < 2; u++) {
            const int ra = u * 64 + rl + h * 128;                    // A unit rows
            const int rb = u * 32 + rl + (rl & 32) + h * 128;        // B unit rows
            gOffA[u][h] = (size_t)(row0 + ra) * DIM + scX;
            gOffB[u][h] = (size_t)(col0 + rb) * DIM + scX;
            lOffA[u][h] = ra * 128 + cp * 16;
            lOffB[u][h] = 32768 + rb * 128 + cp * 16;
        }
    }
    auto stageA = [&](int kt, int u) {                   // u: 0=alpha, 1=beta
        const int bo = (kt & 1) * 65536;
#pragma unroll
        for (int h = 0; h < 2; h++)
            __builtin_amdgcn_global_load_lds((const AS1 u32*)(A + gOffA[u][h] + kt * 64),
                                             (AS3 u32*)((char*)lds + bo + lOffA[u][h]), 16, 0, 0);
    };
    auto stageB = [&](int kt, int u) {                   // u: 0=B0, 1=B1
        const int bo = (kt & 1) * 65536;
#pragma unroll
        for (int h = 0; h < 2; h++)
            __builtin_amdgcn_global_load_lds((const AS1 u32*)(B + gOffB[u][h] + kt * 64),
                                             (AS3 u32*)((char*)lds + bo + lOffB[u][h]), 16, 0, 0);
    };

    s16x8 aF[4][2], b0F[2][2], b1F[2][2];   // 64 VGPR, never live across back-edge

    auto readA = [&](s16x8 (&dst)[4][2], const u16* base, int ib) {
#pragma unroll
        for (int kk = 0; kk < 2; kk++) {
            const int soff = s0 ^ (kk * 32);
#pragma unroll
            for (int i = 0; i < 4; i++)
                dst[i][kk] = *(const s16x8*)&base[(wRow + (ib + i) * 16 + lr) * 64 + soff];
        }
    };
    auto readB = [&](s16x8 (&dst)[2][2], const u16* base, int jb) {
#pragma unroll
        for (int kk = 0; kk < 2; kk++) {
            const int soff = s0 ^ (kk * 32);
#pragma unroll
            for (int j = 0; j < 2; j++)
                dst[j][kk] = *(const s16x8*)&base[(wCol + (jb + j) * 16 + lr) * 64 + soff];
        }
    };

#define MFMA_Q(AF, BF, IO, JO)                                                  \
    __builtin_amdgcn_s_setprio(1);                                              \
    _Pragma("unroll")                                                           \
    for (int kk = 0; kk < 2; kk++)                                              \
        _Pragma("unroll")                                                       \
        for (int i = 0; i < 4; i++)                                             \
            _Pragma("unroll")                                                   \
            for (int j = 0; j < 2; j++)                                         \
                acc[(IO) + i][(JO) + j] = __builtin_amdgcn_mfma_f32_16x16x32_bf16( \
                    AF[i][kk], BF[j][kk], acc[(IO) + i][(JO) + j], 0, 0, 0);    \
    __builtin_amdgcn_s_setprio(0);

    // ---- prologue: tile 0 complete (8 loads) + alpha/beta of tile 1 (4 loads) ----
    stageA(0, 0);  stageA(0, 1);  stageB(0, 0);  stageB(0, 1);
    stageA(1, 0);  stageA(1, 1);
    VMCNT(4);                               // tile 0 resident; {alpha,beta}(1) in flight
    BAR();

    for (int kt = 0; kt < 8; kt++) {
        const u16* bufA = lds + (kt & 1) * 32768;
        const u16* bufB = bufA + 16384;

        // ---- P0: ih0 x jh0 ----
        readA(aF, bufA, 0);                     // alpha(kt): 8 x ds_read_b128
        readB(b0F, bufB, 0);                    // B0(kt):    4 x ds_read_b128
        if (kt + 1 < 8) stageB(kt + 1, 0);
        BAR();
        MFMA_Q(aF, b0F, 0, 0)
        BAR();

        // ---- P1: ih0 x jh1 ----
        readB(b1F, bufB, 2);                    // B1(kt)
        if (kt + 1 < 8) stageB(kt + 1, 1);
        BAR();
        MFMA_Q(aF, b1F, 0, 2)
        BAR();

        // ---- P2: ih1 x jh0 ----
        readA(aF, bufA, 4);                     // beta(kt), reuses aF registers
        if (kt + 2 < 8) stageA(kt + 2, 0);
        BAR();
        MFMA_Q(aF, b0F, 4, 0)
        BAR();

        // ---- P3: ih1 x jh1 ----
        if (kt + 2 < 8) stageA(kt + 2, 1);
        BAR();
        MFMA_Q(aF, b1F, 4, 2)
        if (kt < 6)       { VMCNT(4); }         // tile kt+1 resident; A(kt+2) in flight
        else if (kt == 6) { VMCNT(0); }         // tail drain for tile 7
        BAR();                                  // publishes staging across waves
    }

    // ---- epilogue: row-min over this block's 256 cols -> threshold -> margin-append ----
    float c2v[4];
#pragma unroll
    for (int j = 0; j < 4; j++) c2v[j] = c2[col0 + wCol + j * 16 + lr];

#pragma unroll
    for (int i = 0; i < 8; i++) {
#pragma unroll
        for (int r = 0; r < 4; r++) {
            float v0 = c2v[0] - 2.0f * acc[i][0][r];
            float v1 = c2v[1] - 2.0f * acc[i][1][r];
            float v2 = c2v[2] - 2.0f * acc[i][2][r];
            float v3 = c2v[3] - 2.0f * acc[i][3][r];
            float mn = fminf(fminf(v0, v1), fminf(v2, v3));
#pragma unroll
            for (int mask = 1; mask < 16; mask <<= 1)
                mn = fminf(mn, __shfl_xor(mn, mask));
            if (lr == 0) atomicMin(&mrow[wRow + i * 16 + quad * 4 + r], encf(mn));
        }
    }
    __syncthreads();
#pragma unroll
    for (int i = 0; i < 8; i++) {
#pragma unroll
        for (int r = 0; r < 4; r++) {
            const int lrow = wRow + i * 16 + quad * 4 + r;
            const float th = decf(mrow[lrow]) + MARGIN;
            const int grow = row0 + lrow;
#pragma unroll
            for (int j = 0; j < 4; j++) {
                float s = c2v[j] - 2.0f * acc[i][j][r];
                if (s < th) {
                    u32 idx = atomicAdd(&cnt[grow], 1u);
                    if (idx < CAP)
                        cand[(size_t)grow * CAP + idx] =
                            make_uint2(__float_as_uint(s), (u32)(col0 + wCol + j * 16 + lr));
                }
            }
        }
    }
}

// ---------------- pass 2: exact rescore (fp64 dot, np-fp32 pipeline) + gather + PE ----------------
__global__ __launch_bounds__(256) void k_fin(const float* __restrict__ x,
                                             const float* __restrict__ cb,
                                             const float* __restrict__ c2,
                                             const float* __restrict__ x2,
                                             const u32* __restrict__ cnt,
                                             const uint2* __restrict__ cand,
                                             float* __restrict__ out) {
    const int row  = (blockIdx.x * 256 + threadIdx.x) >> 6;   // one wave per row
    const int lane = threadIdx.x & 63;
    int n = (int)cnt[row];
    if (n > CAP) n = CAP;
    if (n < 0) n = 0;
    const uint2* cd = cand + (size_t)row * CAP;

    float m = 3.4028235e38f;
    for (int i = lane; i < n; i += 64) m = fminf(m, __uint_as_float(cd[i].x));
#pragma unroll
    for (int mask = 32; mask; mask >>= 1) m = fminf(m, __shfl_xor(m, mask));
    const float thr = m + RESCORE_MARGIN;

    const float* xr = x + (size_t)row * DIM + lane * 8;
    float4 xv0 = *(const float4*)xr;
    float4 xv1 = *(const float4*)(xr + 4);
    const float x2v = x2[row];

    u64 best = ~0ull;
    for (int i = 0; i < n; i++) {
        uint2 e = cd[i];
        float sa = __uint_as_float(e.x);
        u32 ci = (e.y < (u32)CODES) ? e.y : 0u;                // harden gather index
        if (sa <= thr) {                                       // wave-uniform branch
            const float* cr = cb + (size_t)ci * DIM + lane * 8;
            float4 c0 = *(const float4*)cr;
            float4 c1 = *(const float4*)(cr + 4);
            double d = (double)xv0.x * c0.x + (double)xv0.y * c0.y +
                       (double)xv0.z * c0.z + (double)xv0.w * c0.w +
                       (double)xv1.x * c1.x + (double)xv1.y * c1.y +
                       (double)xv1.z * c1.z + (double)xv1.w * c1.w;
#pragma unroll
            for (int mask = 32; mask; mask >>= 1) d += __shfl_xor(d, mask);
            float dot = (float)d;
            float s32 = (x2v - 2.0f * dot) + c2[ci];           // np fp32 pipeline
            u64 key = ((u64)encf(s32) << 32) | (u64)ci;        // lowest-index tie-break
            best = best < key ? best : key;
        }
    }
    u32 wcol = (u32)(best & 0xffffffffu);
    if (wcol >= (u32)CODES) wcol = 0;                          // unreachable safety

    const float* cw = cb + (size_t)wcol * DIM + lane * 8;
    float4 q0 = *(const float4*)cw;
    float4 q1 = *(const float4*)(cw + 4);
    const int spos = row & (SEQ - 1);
    float pe[8];
#pragma unroll
    for (int ii = 0; ii < 4; ii++) {
        int ipair = lane * 4 + ii;
        float dt  = expf((float)(2 * ipair) * (-0.017988946039035083f)); // ln(1e4)/512
        float ang = (float)spos * dt;
        float sv, cv;
        sincosf(ang, &sv, &cv);
        pe[2 * ii]     = sv;
        pe[2 * ii + 1] = cv;
    }
    float4* op = (float4*)(out + (size_t)row * DIM + lane * 8);
    op[0] = make_float4(q0.x + pe[0], q0.y + pe[1], q0.z + pe[2], q0.w + pe[3]);
    op[1] = make_float4(q1.x + pe[4], q1.y + pe[5], q1.z + pe[6], q1.w + pe[7]);
}

extern "C" void kernel_launch(void* const* d_in, const int* in_sizes, int n_in,
                              void* d_out, int out_size, void* d_ws, size_t ws_size,
                              hipStream_t stream) {
    const float* x  = (const float*)d_in[0];   // [8,2048,512]
    const float* cb = (const float*)d_in[1];   // [8192,512]
    float* out = (float*)d_out;

    char* ws = (char*)d_ws;
    u16*   Abf  = (u16*)ws;                                   // 16 MiB
    u16*   Bbf  = (u16*)(ws + 16777216);                      //  8 MiB
    float* c2   = (float*)(ws + 16777216 + 8388608);          // 32 KiB
    float* x2   = (float*)(ws + 16777216 + 8388608 + 32768);  // 64 KiB
    u32*   cnt  = (u32*)(ws + 16777216 + 8388608 + 32768 + 65536);            // 64 KiB
    uint2* cand = (uint2*)(ws + 16777216 + 8388608 + 32768 + 65536 + 65536);  // 16 MiB

    k_prep<<<dim3(384), dim3(256), 0, stream>>>(x, cb, Abf, Bbf, x2, c2, cnt);
    k_vq<<<dim3(2048), dim3(512), 0, stream>>>(Abf, Bbf, c2, cnt, cand);
    k_fin<<<dim3(4096), dim3(256), 0, stream>>>(x, cb, c2, x2, cnt, cand, out);
}